// Round 18
// baseline (174.567 us; speedup 1.0000x reference)
//
#include <hip/hip_runtime.h>
#include <hip/hip_bf16.h>

// ---------------------------------------------------------------------------
// SimpleSelfAttention: out = softmax((xWq^T+bq)(xWk^T+bk)^T / 32) (xWv^T+bv)
// B=4, S=2048, E=1024, fp32 in/out. Internally bf16 MFMA, fp32 accum.
//
// R18 algebraic refactor: Q,K never materialized.
//   S = x (Wq^T Wk) x^T /32 + u 1^T + 1 v^T + c
//   M'' = Wk^T Wq  (2.1 GF, split-K grid 8x8x4 fp32 partials + combine)
//   y   = x . M''^T (17.2 GF)  ->  S = y x^T /32 + u_i + v_j (+c in u)
//   u = x.(bk^T Wq)^T/32, v = x.(bq^T Wk)^T/32, c = bq.bk/32 (tiny matvecs)
// Replaces the 34.4 GF QK projection (47.5us) with ~36us of work.
//
// gemm256 (8-phase, conflict-free XOR LDS, R15-17): scores only; EPI=1
// epilogue: exp(acc*scale + u[i] + v[j]) + per-64col psum partials.
// gemm97 (2-barrier 128x128, 3 blocks/CU): M''-split, y, VT, PV.
// Softmax folded (R11-17): psum -> reduce_rs -> PV epilogue x 1/rs.
//
// ws: y@0 (16MB) | Mpart fp32 @8M1 (16MB, dead after combine) |
//     VT@8M1 (16MB, after y) | P@16M1 (32MB) ; rs@0 over dead y
// d_out scratch: xb@0 | WqT@8M1 | WkT@9M1 | Wvb@10M1 | psum/u/v/wu/wv/c@11M1
//     | Mb@12M1 ; all dead before PV writes d_out.
// order: cvt -> tcvt -> wuv -> uv -> M''split -> combine -> y -> VT
//        -> scores -> reduce_rs -> PV
// ---------------------------------------------------------------------------

typedef __attribute__((ext_vector_type(8))) short bf16x8;
typedef __attribute__((ext_vector_type(4))) short bf16x4;
typedef __attribute__((ext_vector_type(4))) float f32x4;

#define DEVI static __device__ __forceinline__

DEVI short to_bf16(float f) {
    unsigned u = __builtin_bit_cast(unsigned, f);
    u += 0x7fffu + ((u >> 16) & 1u);          // RNE (finite/normal inputs)
    return (short)(u >> 16);
}
DEVI float from_bf16(short s) {
    return __builtin_bit_cast(float, (unsigned)((unsigned short)s) << 16);
}

DEVI void gload_lds16(const short* g, short* l) {
    __builtin_amdgcn_global_load_lds(
        (const __attribute__((address_space(1))) void*)g,
        (__attribute__((address_space(3))) void*)l, 16, 0, 0);
}

#define BAR() __builtin_amdgcn_s_barrier()

// ============================ gemm256 (8-phase) ============================
// C[z][M][N] = scale*A[z].B[z]^T. bf16 K-major. K%64==0, K>=192.
// EPI: 0=plain, 1=exp(acc*scale + b0[z*2048+m0+row] + b1[z*2048+n0+col])
//      + psum partials (softmax-fold path).
template<int EPI, typename TOUT>
__global__ __launch_bounds__(512, 1)
void gemm256(const short* __restrict__ A, long lda, long bsA,
             const short* __restrict__ B, long ldb, long bsB,
             const float* __restrict__ b0, const float* __restrict__ b1,
             TOUT* __restrict__ C, long ldc, long bsC,
             int K, float scale, float* __restrict__ ps)
{
    // half-tile = [128 prow][8 pchunk] 16B chunks (8192 shorts)
    __shared__ __align__(16) short Al[2][2][128 * 64];
    __shared__ __align__(16) short Bl[2][2][128 * 64];

    const int tid = threadIdx.x;
    const int z = blockIdx.z;
    const int gx = gridDim.x;
    const int nwg = gx * gridDim.y;
    const int id = blockIdx.y * gx + blockIdx.x;
    const int id2 = (id & 7) * (nwg >> 3) + (id >> 3);   // XCD swizzle (nwg%8==0)
    const long m0 = (long)(id2 / gx) * 256;
    const long n0 = (long)(id2 % gx) * 256;

    const short* Ab = A + (long)z * bsA + m0 * lda;
    const short* Bb = B + (long)z * bsB + n0 * ldb;

    const int wv = tid >> 6;
    const int wm = wv >> 2;            // 0..1 : M half
    const int wn = wv & 3;             // 0..3 : 64-col N strip
    const int lane = tid & 63;
    const int lrow = lane & 15;
    const int q = lane >> 4;           // k-quarter within a 32-k half

    const int NT = K >> 6;             // BK=64, NT>=3

    auto stA = [&](int t, int kh) {
        const long k0 = (long)t * 64 + kh * 32;
        short* dst = &Al[t & 1][kh][0];
        #pragma unroll
        for (int i = 0; i < 2; ++i) {
            int s = i * 512 + tid;
            int prow = s >> 3;
            int pch = (s & 7) ^ (prow & 7);
            int row = prow * 2 + (pch >> 2);
            gload_lds16(Ab + (long)row * lda + k0 + (pch & 3) * 8,
                        &dst[s * 8]);
        }
    };
    auto stB = [&](int t, int kh) {
        const long k0 = (long)t * 64 + kh * 32;
        short* dst = &Bl[t & 1][kh][0];
        #pragma unroll
        for (int i = 0; i < 2; ++i) {
            int s = i * 512 + tid;
            int prow = s >> 3;
            int pch = (s & 7) ^ (prow & 7);
            int row = prow * 2 + (pch >> 2);
            gload_lds16(Bb + (long)row * ldb + k0 + (pch & 3) * 8,
                        &dst[s * 8]);
        }
    };

    bf16x8 af[4], bf[4];
    auto rdA = [&](int b, int kh, int mh) {
        #pragma unroll
        for (int m = 0; m < 4; ++m) {
            int row = wm * 128 + (mh * 4 + m) * 16 + lrow;
            int prow = row >> 1;
            int pch = (((row & 1) * 4 + q)) ^ (prow & 7);
            af[m] = *(const bf16x8*)&Al[b][kh][prow * 64 + pch * 8];
        }
    };
    auto rdB = [&](int b, int kh) {
        #pragma unroll
        for (int n = 0; n < 4; ++n) {
            int row = wn * 64 + n * 16 + lrow;
            int prow = row >> 1;
            int pch = (((row & 1) * 4 + q)) ^ (prow & 7);
            bf[n] = *(const bf16x8*)&Bl[b][kh][prow * 64 + pch * 8];
        }
    };

    f32x4 acc[8][4] = {};

    // prologue: tile0 all 4 half-tiles + tile1 k0 half-tiles (12 loads)
    stA(0, 0); stB(0, 0); stA(0, 1); stB(0, 1);
    stA(1, 0); stB(1, 0);
    asm volatile("s_waitcnt vmcnt(4)" ::: "memory");   // tile0 landed
    __builtin_amdgcn_sched_barrier(0);
    BAR();

    for (int t = 0; t < NT; ++t) {
        const int b = t & 1;
        // ---- ph1: m0-3 x kk0 (stages (t+1).Ak1 -> buf^1)
        rdA(b, 0, 0); rdB(b, 0);
        if (t + 1 < NT) stA(t + 1, 1);
        BAR();
        __builtin_amdgcn_s_setprio(1);
        #pragma unroll
        for (int m = 0; m < 4; ++m)
            #pragma unroll
            for (int n = 0; n < 4; ++n)
                acc[m][n] = __builtin_amdgcn_mfma_f32_16x16x32_bf16(
                    af[m], bf[n], acc[m][n], 0, 0, 0);
        __builtin_amdgcn_s_setprio(0);
        BAR();
        // ---- ph2: m4-7 x kk0 (stages (t+1).Bk1)
        rdA(b, 0, 1);
        if (t + 1 < NT) stB(t + 1, 1);
        BAR();
        __builtin_amdgcn_s_setprio(1);
        #pragma unroll
        for (int m = 0; m < 4; ++m)
            #pragma unroll
            for (int n = 0; n < 4; ++n)
                acc[4 + m][n] = __builtin_amdgcn_mfma_f32_16x16x32_bf16(
                    af[m], bf[n], acc[4 + m][n], 0, 0, 0);
        __builtin_amdgcn_s_setprio(0);
        if (t < NT - 1) asm volatile("s_waitcnt vmcnt(8)" ::: "memory");
        else            asm volatile("s_waitcnt vmcnt(0)" ::: "memory");
        __builtin_amdgcn_sched_barrier(0);
        BAR();   // t.Ak1/Bk1 landed for all waves -> ph3 may read
        // ---- ph3: m0-3 x kk1 (stages (t+2).Ak0 over dead t.Ak0)
        rdA(b, 1, 0); rdB(b, 1);
        if (t + 2 < NT) stA(t + 2, 0);
        BAR();
        __builtin_amdgcn_s_setprio(1);
        #pragma unroll
        for (int m = 0; m < 4; ++m)
            #pragma unroll
            for (int n = 0; n < 4; ++n)
                acc[m][n] = __builtin_amdgcn_mfma_f32_16x16x32_bf16(
                    af[m], bf[n], acc[m][n], 0, 0, 0);
        __builtin_amdgcn_s_setprio(0);
        BAR();
        // ---- ph4: m4-7 x kk1 (stages (t+2).Bk0 over dead t.Bk0)
        rdA(b, 1, 1);
        if (t + 2 < NT) stB(t + 2, 0);
        BAR();
        __builtin_amdgcn_s_setprio(1);
        #pragma unroll
        for (int m = 0; m < 4; ++m)
            #pragma unroll
            for (int n = 0; n < 4; ++n)
                acc[4 + m][n] = __builtin_amdgcn_mfma_f32_16x16x32_bf16(
                    af[m], bf[n], acc[4 + m][n], 0, 0, 0);
        __builtin_amdgcn_s_setprio(0);
        if (t < NT - 2) asm volatile("s_waitcnt vmcnt(8)" ::: "memory");
        else            asm volatile("s_waitcnt vmcnt(0)" ::: "memory");
        __builtin_amdgcn_sched_barrier(0);
        BAR();   // (t+1).Ak0/Bk0 landed -> next tile ph1 may read
    }

    // epilogue: C/D layout col=lane&15, row=q*4+reg (verified m89)
    TOUT* Cb = C + (long)z * bsC + m0 * ldc + n0;
    float vvv[4];
    if constexpr (EPI == 1) {
        #pragma unroll
        for (int n = 0; n < 4; ++n)
            vvv[n] = b1[(long)z * 2048 + n0 + wn * 64 + n * 16 + lrow];
    }
    #pragma unroll
    for (int m = 0; m < 8; ++m) {
        #pragma unroll
        for (int r = 0; r < 4; ++r) {
            int row = wm * 128 + m * 16 + q * 4 + r;
            float uval = 0.f, rsum = 0.f;
            if constexpr (EPI == 1)
                uval = b0[(long)z * 2048 + m0 + row];
            #pragma unroll
            for (int n = 0; n < 4; ++n) {
                int col = wn * 64 + n * 16 + lrow;
                float v = acc[m][n][r] * scale;
                if constexpr (EPI == 1) {
                    v = __expf(v + uval + vvv[n]);
                    rsum += v;
                }
                if constexpr (sizeof(TOUT) == 2)
                    Cb[(long)row * ldc + col] = to_bf16(v);
                else
                    Cb[(long)row * ldc + col] = v;
            }
            if constexpr (EPI == 1) {
                rsum += __shfl_xor(rsum, 1);
                rsum += __shfl_xor(rsum, 2);
                rsum += __shfl_xor(rsum, 4);
                rsum += __shfl_xor(rsum, 8);
                if (lrow == 0) {
                    int j = (int)(n0 >> 6) + wn;     // 0..31
                    ps[((long)z * 32 + j) * 2048 + m0 + row] = rsum;
                }
            }
        }
    }
}

// ===================== gemm97 (proven 2-barrier core) ======================
// BIAS: 0=none, 2=row bias b0[m]. EPI: 0=plain, 2=v *= 1/rs[row].
template<int BIAS, int EPI, typename TOUT>
__global__ __launch_bounds__(256, 3)
void gemm97(const short* __restrict__ A, long lda, long bsA,
            const short* __restrict__ B, long ldb, long bsB,
            const float* __restrict__ b0,
            TOUT* __restrict__ C, long ldc, long bsC, int K, float scale,
            const float* __restrict__ rs, long rsLD)
{
    __shared__ __align__(16) short As[128 * 64];
    __shared__ __align__(16) short Bs[128 * 64];

    const int tid = threadIdx.x;
    const int z = blockIdx.z;

    const int gx = gridDim.x;
    const int nwg = gx * gridDim.y;
    const int id = blockIdx.y * gx + blockIdx.x;
    const int id2 = (id & 7) * (nwg >> 3) + (id >> 3);
    const long m0 = (long)(id2 / gx) * 128;
    const long n0 = (long)(id2 % gx) * 128;

    const short* Ab = A + (long)z * bsA + m0 * lda;
    const short* Bb = B + (long)z * bsB + n0 * ldb;

    const int wv = tid >> 6;
    const int lane = tid & 63;
    const int wr = (wv >> 1) * 64;
    const int wc = (wv & 1) * 64;
    const int lrow = lane & 15;
    const int q = lane >> 4;

    const int NT = K >> 6;

    auto stage = [&](int t) {
        const long k0 = (long)t * 64;
        #pragma unroll
        for (int i = 0; i < 4; ++i) {
            int s = i * 256 + tid;
            int row = s >> 3;
            int src = (s & 7) ^ (row & 7);
            gload_lds16(Ab + (long)row * lda + k0 + src * 8, &As[s * 8]);
        }
        #pragma unroll
        for (int i = 0; i < 4; ++i) {
            int s = i * 256 + tid;
            int row = s >> 3;
            int src = (s & 7) ^ (row & 7);
            gload_lds16(Bb + (long)row * ldb + k0 + src * 8, &Bs[s * 8]);
        }
    };

    f32x4 acc[4][4] = {};

    for (int t = 0; t < NT; ++t) {
        if (t) BAR();
        stage(t);
        asm volatile("s_waitcnt vmcnt(0)" ::: "memory");
        __builtin_amdgcn_sched_barrier(0);
        BAR();

        bf16x8 af[4][2], bf[4][2];
        #pragma unroll
        for (int m = 0; m < 4; ++m) {
            int row = wr + m * 16 + lrow;
            #pragma unroll
            for (int kk = 0; kk < 2; ++kk) {
                int ch = (kk * 4 + q) ^ (row & 7);
                af[m][kk] = *(const bf16x8*)&As[row * 64 + ch * 8];
            }
        }
        #pragma unroll
        for (int n = 0; n < 4; ++n) {
            int row = wc + n * 16 + lrow;
            #pragma unroll
            for (int kk = 0; kk < 2; ++kk) {
                int ch = (kk * 4 + q) ^ (row & 7);
                bf[n][kk] = *(const bf16x8*)&Bs[row * 64 + ch * 8];
            }
        }

        __builtin_amdgcn_s_setprio(1);
        #pragma unroll
        for (int m = 0; m < 4; ++m)
            #pragma unroll
            for (int n = 0; n < 4; ++n)
                #pragma unroll
                for (int kk = 0; kk < 2; ++kk)
                    acc[m][n] = __builtin_amdgcn_mfma_f32_16x16x32_bf16(
                        af[m][kk], bf[n][kk], acc[m][n], 0, 0, 0);
        __builtin_amdgcn_s_setprio(0);
    }

    TOUT* Cb = C + (long)z * bsC + m0 * ldc + n0;
    #pragma unroll
    for (int m = 0; m < 4; ++m) {
        #pragma unroll
        for (int r = 0; r < 4; ++r) {
            int row = wr + m * 16 + q * 4 + r;
            float iv = 1.0f;
            if constexpr (EPI == 2)
                iv = 1.0f / rs[(long)z * rsLD + m0 + row];
            #pragma unroll
            for (int n = 0; n < 4; ++n) {
                int col = wc + n * 16 + lrow;
                float v = acc[m][n][r] * scale;
                if constexpr (BIAS == 2) v += b0[m0 + row];
                if constexpr (EPI == 2) v *= iv;
                if constexpr (sizeof(TOUT) == 2)
                    Cb[(long)row * ldc + col] = to_bf16(v);
                else
                    Cb[(long)row * ldc + col] = v;
            }
        }
    }
}

// cvt: grid (512, 9). y<8: x chunks (fp32->bf16). y=8: Wv -> Wvb.
__global__ __launch_bounds__(256)
void cvt_all(const float* __restrict__ x, const float* __restrict__ wvf,
             short* __restrict__ xb, short* __restrict__ wvb)
{
    const int y = blockIdx.y;
    const float* src;
    short* dst;
    long i;
    if (y < 8) {
        src = x; dst = xb;
        i = ((long)y * 512 + blockIdx.x) * 256 + threadIdx.x;
    } else {
        src = wvf; dst = wvb;
        i = (long)blockIdx.x * 256 + threadIdx.x;
    }
    float4 a = ((const float4*)src)[2 * i];
    float4 b = ((const float4*)src)[2 * i + 1];
    bf16x8 o = { to_bf16(a.x), to_bf16(a.y), to_bf16(a.z), to_bf16(a.w),
                 to_bf16(b.x), to_bf16(b.y), to_bf16(b.z), to_bf16(b.w) };
    *(bf16x8*)&dst[i * 8] = o;
}

// transpose+cvt: WT[i][j] = bf16(W[j][i]); grid (32,32,2), z: Wq->d0, Wk->d1
__global__ __launch_bounds__(256)
void tcvt(const float* __restrict__ s0, const float* __restrict__ s1,
          short* __restrict__ d0, short* __restrict__ d1)
{
    __shared__ float tl[32][33];
    const float* src = blockIdx.z ? s1 : s0;
    short* dst = blockIdx.z ? d1 : d0;
    const int r0 = blockIdx.x * 32, c0 = blockIdx.y * 32;
    const int tid = threadIdx.x;
    #pragma unroll
    for (int i = 0; i < 4; ++i) {
        int qq = tid + 256 * i;
        int r = qq >> 5, c = qq & 31;
        tl[r][c] = src[(long)(r0 + r) * 1024 + c0 + c];
    }
    __syncthreads();
    #pragma unroll
    for (int i = 0; i < 4; ++i) {
        int qq = tid + 256 * i;
        int r = qq >> 5, c = qq & 31;
        dst[(long)(c0 + r) * 1024 + r0 + c] = to_bf16(tl[c][r]);
    }
}

// wu[k] = (WqT row k . bk)/32 ; wv[k] = (WkT row k . bq)/32 ; c = bq.bk/32
// grid (256, 3): y=0 -> wu, y=1 -> wv, y=2 (block 0 only) -> c.
__global__ __launch_bounds__(256)
void wuv(const short* __restrict__ WqT, const short* __restrict__ WkT,
         const float* __restrict__ bq, const float* __restrict__ bk,
         float* __restrict__ wu, float* __restrict__ wv, float* __restrict__ cb)
{
    const int y = blockIdx.y;
    if (y == 2) {
        if (blockIdx.x) return;
        float s = 0.f;
        for (int m = threadIdx.x; m < 1024; m += 256) s += bq[m] * bk[m];
        #pragma unroll
        for (int off = 32; off > 0; off >>= 1) s += __shfl_xor(s, off);
        __shared__ float red[4];
        if ((threadIdx.x & 63) == 0) red[threadIdx.x >> 6] = s;
        __syncthreads();
        if (threadIdx.x == 0)
            cb[0] = (red[0] + red[1] + red[2] + red[3]) * 0.03125f;
        return;
    }
    const short* W = y ? WkT : WqT;
    const float* b = y ? bq : bk;
    const int wave = threadIdx.x >> 6, lane = threadIdx.x & 63;
    const int k = blockIdx.x * 4 + wave;
    const short* p = W + (long)k * 1024 + lane * 16;
    float s = 0.f;
    #pragma unroll
    for (int h = 0; h < 2; ++h) {
        bf16x8 xv = *(const bf16x8*)(p + h * 8);
        #pragma unroll
        for (int j = 0; j < 8; ++j)
            s += from_bf16(xv[j]) * b[lane * 16 + h * 8 + j];
    }
    #pragma unroll
    for (int off = 32; off > 0; off >>= 1) s += __shfl_xor(s, off);
    if (lane == 0) (y ? wv : wu)[k] = s * 0.03125f;
}

// u[i] = xb_i . wu + c ; v[i] = xb_i . wv ; wave per row, grid 2048.
__global__ __launch_bounds__(256)
void uv_rows(const short* __restrict__ xb, const float* __restrict__ wu,
             const float* __restrict__ wv, const float* __restrict__ cb,
             float* __restrict__ u, float* __restrict__ v)
{
    const int wave = threadIdx.x >> 6, lane = threadIdx.x & 63;
    const long row = (long)blockIdx.x * 4 + wave;
    const short* p = xb + row * 1024 + lane * 16;
    float su = 0.f, sv = 0.f;
    #pragma unroll
    for (int h = 0; h < 2; ++h) {
        bf16x8 xv = *(const bf16x8*)(p + h * 8);
        #pragma unroll
        for (int j = 0; j < 8; ++j) {
            float xf = from_bf16(xv[j]);
            int idx = lane * 16 + h * 8 + j;
            su += xf * wu[idx];
            sv += xf * wv[idx];
        }
    }
    #pragma unroll
    for (int off = 32; off > 0; off >>= 1) {
        su += __shfl_xor(su, off);
        sv += __shfl_xor(sv, off);
    }
    if (lane == 0) { u[row] = su + cb[0]; v[row] = sv; }
}

// Mb[i] = bf16(sum of 4 fp32 K-split partials); grid 1024, 4 elems/thread.
__global__ __launch_bounds__(256)
void combine_m(const float* __restrict__ mp, short* __restrict__ mb)
{
    long i4 = (long)blockIdx.x * 256 + threadIdx.x;   // < 262144
    float4 a = ((const float4*)mp)[i4];
    float4 b = ((const float4*)(mp + 1048576))[i4];
    float4 c = ((const float4*)(mp + 2097152))[i4];
    float4 d = ((const float4*)(mp + 3145728))[i4];
    bf16x4 o = { to_bf16(a.x + b.x + c.x + d.x),
                 to_bf16(a.y + b.y + c.y + d.y),
                 to_bf16(a.z + b.z + c.z + d.z),
                 to_bf16(a.w + b.w + c.w + d.w) };
    *(bf16x4*)&mb[i4 * 4] = o;
}

// rs[row] = sum_{j<32} ps[(z*32+j)*2048 + r]
__global__ __launch_bounds__(256)
void reduce_rs(const float* __restrict__ ps, float* __restrict__ rs)
{
    int row = blockIdx.x * 256 + threadIdx.x;   // 0..8191
    int z = row >> 11, r = row & 2047;
    const float* p = ps + (long)z * 32 * 2048 + r;
    float s = 0.f;
    #pragma unroll
    for (int j = 0; j < 32; ++j) s += p[j * 2048];
    rs[row] = s;
}

extern "C" void kernel_launch(void* const* d_in, const int* in_sizes, int n_in,
                              void* d_out, int out_size, void* d_ws, size_t ws_size,
                              hipStream_t stream)
{
    (void)in_sizes; (void)n_in; (void)out_size; (void)ws_size;

    const float* x  = (const float*)d_in[0];
    const float* Wq = (const float*)d_in[1];
    const float* bq = (const float*)d_in[2];
    const float* Wk = (const float*)d_in[3];
    const float* bk = (const float*)d_in[4];
    const float* Wv = (const float*)d_in[5];
    const float* bv = (const float*)d_in[6];
    float* out = (float*)d_out;

    const int S = 2048, E = 1024;
    const long M1 = 1024l * 1024;

    // ws regions
    short* w   = (short*)d_ws;
    short* yb  = w;                   // [8192][1024] bf16 (16MB)
    float* Mp  = (float*)(w + 8 * M1);// [4][1024][1024] fp32 partials (16MB)
    short* VT  = w + 8 * M1;          // [4][1024][2048] bf16 (16MB, after y)
    short* P   = w + 16 * M1;         // [4][2048][2048] bf16 exp(scores) (32MB)
    float* rs  = (float*)w;           // [8192] fp32 over dead y

    // d_out scratch (all dead before PV writes d_out)
    short* dows = (short*)d_out;
    short* xb  = dows;                // [8192][1024] bf16 (16MB)
    short* WqT = dows + 8 * M1;       // [1024][1024] bf16 (2MB)
    short* WkT = dows + 9 * M1;
    short* Wvb = dows + 10 * M1;
    float* psum = (float*)(dows + 11 * M1);      // [4][32][2048] (1MB)
    float* u   = psum + 262144;       // [8192]
    float* v   = u + 8192;            // [8192]
    float* wu  = v + 8192;            // [1024]
    float* wvv = wu + 1024;           // [1024]
    float* cb  = wvv + 1024;          // [1]
    short* Mb  = dows + 12 * M1;      // [1024][1024] bf16 (2MB)

    dim3 blk(256), blk5(512);

    // 1. xb, Wvb ; 2. WqT, WkT (transposed cvt)
    cvt_all<<<dim3(512, 9), blk, 0, stream>>>(x, Wv, xb, Wvb);
    tcvt<<<dim3(32, 32, 2), blk, 0, stream>>>(Wq, Wk, WqT, WkT);

    // 3. wu, wv, c ; 4. u, v
    wuv<<<dim3(256, 3), blk, 0, stream>>>(WqT, WkT, bq, bk, wu, wvv, cb);
    uv_rows<<<dim3(2048), blk, 0, stream>>>(xb, wu, wvv, cb, u, v);

    // 5. M'' split-K: Mp[z] = WkT . WqT^T over K-chunk z*256 (grid 8x8x4)
    gemm97<0, 0, float><<<dim3(8, 8, 4), blk, 0, stream>>>(
        WkT, E, 256, WqT, E, 256, nullptr, Mp, E, M1, 256, 1.0f, nullptr, 0);

    // 6. Mb = bf16(sum of partials)
    combine_m<<<dim3(1024), blk, 0, stream>>>(Mp, Mb);

    // 7. y = xb . Mb^T  (M=8192, N=1024, K=1024): grid 8x64
    gemm97<0, 0, short><<<dim3(8, 64, 1), blk, 0, stream>>>(
        xb, E, 0, Mb, E, 0, nullptr, yb, E, 0, E, 1.0f, nullptr, 0);

    // 8. VT[z] = Wvb xb[z]^T + bv (row bias) -> over dead Mp
    gemm97<2, 0, short><<<dim3(16, 8, 4), blk, 0, stream>>>(
        Wvb, E, 0, xb, E, 2 * M1, bv, VT, S, 2 * M1, E, 1.0f, nullptr, 0);

    // 9. scores: P[z] = exp(y x^T /32 + u_i + v_j) + psum  (grid 8x8x4)
    gemm256<1, short><<<dim3(8, 8, 4), blk5, 0, stream>>>(
        yb, E, 2 * M1, xb, E, 2 * M1, u, v, P, S, 4 * M1, E, 0.03125f, psum);

    // 10. rs over dead y
    reduce_rs<<<dim3(32), blk, 0, stream>>>(psum, rs);

    // 11. out[z] = (P[z] VT[z]^T) / rs  (grid 8x16x4, fp32 direct)
    gemm97<0, 2, float><<<dim3(8, 16, 4), blk, 0, stream>>>(
        P, S, 4 * M1, VT, S, 2 * M1, nullptr, out, E, 2 * M1, S, 1.0f, rs, S);
}

// Round 19
// 164.346 us; speedup vs baseline: 1.0622x; 1.0622x over previous
//
#include <hip/hip_runtime.h>
#include <hip/hip_bf16.h>

// ---------------------------------------------------------------------------
// SimpleSelfAttention: out = softmax((xWq^T+bq)(xWk^T+bk)^T / 32) (xWv^T+bv)
// B=4, S=2048, E=1024, fp32 in/out. Internally bf16 MFMA, fp32 accum.
//
// == R19 = revert to R17 (best validated: 164.0 us). R18's algebraic
// refactor (Q,K unmaterialized via M''=Wk^T Wq) regressed to 174.6 us:
// the 11 us QK saving was eaten by a slower scores GEMM (operand L2
// locality) + ~15 us of serial small-kernel chain. ==
//
// gemm256 (8-phase, QK + scores): 256x256 tile, BK=64, 8 waves (512 thr),
// per-wave out 128x64. LDS 128KB: [op][buf(2)][kh(2)] half-tiles in
// gemm97's conflict-free XOR geometry ([128 prow][8 chunk], 128B rows;
// R15: bank conflicts 3.1M -> 0).
// Per-phase manual lgkmcnt fences removed (R17: neutral-to-positive) --
// compiler emits counted lgkmcnt for visible ds_reads; manual ordering only
// where the compiler is blind: vmcnt(N)+sched_barrier publishing
// global_load_lds data before the collective barrier. vmcnt counted (8),
// never 0 mid-loop; stage targets provably dead.
//
// gemm97 (2-barrier 128x128, 3 blocks/CU, 80 VGPR no-spill) keeps VT and PV.
// Softmax folded (R11-17 validated): scores epilogue exp + per-64col psum;
// reduce_rs; PV epilogue x 1/rs.
//
// ws: Q@0 | K@8M1 | P@16M1 ; rs over dead Q ; VT@8M1 over dead K
// d_out scratch: xb@0 | Wb@8M1 | psum@11M1 (all dead before PV writes)
// ---------------------------------------------------------------------------

typedef __attribute__((ext_vector_type(8))) short bf16x8;
typedef __attribute__((ext_vector_type(4))) float f32x4;

#define DEVI static __device__ __forceinline__

DEVI short to_bf16(float f) {
    unsigned u = __builtin_bit_cast(unsigned, f);
    u += 0x7fffu + ((u >> 16) & 1u);          // RNE (finite/normal inputs)
    return (short)(u >> 16);
}
DEVI float from_bf16(short s) {
    return __builtin_bit_cast(float, (unsigned)((unsigned short)s) << 16);
}

DEVI void gload_lds16(const short* g, short* l) {
    __builtin_amdgcn_global_load_lds(
        (const __attribute__((address_space(1))) void*)g,
        (__attribute__((address_space(3))) void*)l, 16, 0, 0);
}

#define BAR() __builtin_amdgcn_s_barrier()

// ============================ gemm256 (8-phase) ============================
// C[z][M][N] = scale*A[z].B[z]^T (+bias). bf16 K-major. K%64==0, K>=192.
// BIAS: 0=none, 1=col bias b_z[n]. EPI: 0=plain, 1=exp + psum partials.
template<int BIAS, int EPI, typename TOUT>
__global__ __launch_bounds__(512, 1)
void gemm256(const short* __restrict__ A, long lda, long bsA,
             const short* __restrict__ B, long ldb, long bsB,
             const float* __restrict__ b0, const float* __restrict__ b1,
             const float* __restrict__ b2,
             TOUT* __restrict__ c0, TOUT* __restrict__ c1, TOUT* __restrict__ c2,
             long ldc, long bsC, int K, float scale, float* __restrict__ ps)
{
    // half-tile = [128 prow][8 pchunk] 16B chunks (8192 shorts)
    __shared__ __align__(16) short Al[2][2][128 * 64];
    __shared__ __align__(16) short Bl[2][2][128 * 64];

    const int tid = threadIdx.x;
    const int z = blockIdx.z;
    const int gx = gridDim.x;
    const int nwg = gx * gridDim.y;
    const int id = blockIdx.y * gx + blockIdx.x;
    const int id2 = (id & 7) * (nwg >> 3) + (id >> 3);   // XCD swizzle (nwg%8==0)
    const long m0 = (long)(id2 / gx) * 256;
    const long n0 = (long)(id2 % gx) * 256;

    const short* Ab = A + (long)z * bsA + m0 * lda;
    const short* Bb = B + (long)z * bsB + n0 * ldb;

    const int wv = tid >> 6;
    const int wm = wv >> 2;            // 0..1 : M half
    const int wn = wv & 3;             // 0..3 : 64-col N strip
    const int lane = tid & 63;
    const int lrow = lane & 15;
    const int q = lane >> 4;           // k-quarter within a 32-k half

    const int NT = K >> 6;             // BK=64, NT>=3

    // staging: physical chunk s covers logical (row = 2*(s>>3) + (pch>>2),
    // c = pch&3) where pch = (s&7)^((s>>3)&7). Round-trip verified.
    auto stA = [&](int t, int kh) {
        const long k0 = (long)t * 64 + kh * 32;
        short* dst = &Al[t & 1][kh][0];
        #pragma unroll
        for (int i = 0; i < 2; ++i) {
            int s = i * 512 + tid;
            int prow = s >> 3;
            int pch = (s & 7) ^ (prow & 7);
            int row = prow * 2 + (pch >> 2);
            gload_lds16(Ab + (long)row * lda + k0 + (pch & 3) * 8,
                        &dst[s * 8]);
        }
    };
    auto stB = [&](int t, int kh) {
        const long k0 = (long)t * 64 + kh * 32;
        short* dst = &Bl[t & 1][kh][0];
        #pragma unroll
        for (int i = 0; i < 2; ++i) {
            int s = i * 512 + tid;
            int prow = s >> 3;
            int pch = (s & 7) ^ (prow & 7);
            int row = prow * 2 + (pch >> 2);
            gload_lds16(Bb + (long)row * ldb + k0 + (pch & 3) * 8,
                        &dst[s * 8]);
        }
    };

    bf16x8 af[4], bf[4];
    auto rdA = [&](int b, int kh, int mh) {
        #pragma unroll
        for (int m = 0; m < 4; ++m) {
            int row = wm * 128 + (mh * 4 + m) * 16 + lrow;
            int prow = row >> 1;
            int pch = (((row & 1) * 4 + q)) ^ (prow & 7);
            af[m] = *(const bf16x8*)&Al[b][kh][prow * 64 + pch * 8];
        }
    };
    auto rdB = [&](int b, int kh) {
        #pragma unroll
        for (int n = 0; n < 4; ++n) {
            int row = wn * 64 + n * 16 + lrow;
            int prow = row >> 1;
            int pch = (((row & 1) * 4 + q)) ^ (prow & 7);
            bf[n] = *(const bf16x8*)&Bl[b][kh][prow * 64 + pch * 8];
        }
    };

    f32x4 acc[8][4] = {};

    // prologue: tile0 all 4 half-tiles + tile1 k0 half-tiles (12 loads)
    stA(0, 0); stB(0, 0); stA(0, 1); stB(0, 1);
    stA(1, 0); stB(1, 0);
    asm volatile("s_waitcnt vmcnt(4)" ::: "memory");   // tile0 landed
    __builtin_amdgcn_sched_barrier(0);
    BAR();

    for (int t = 0; t < NT; ++t) {
        const int b = t & 1;
        // ---- ph1: m0-3 x kk0 (reads Ak0, Bk0; stages (t+1).Ak1 -> buf^1)
        rdA(b, 0, 0); rdB(b, 0);
        if (t + 1 < NT) stA(t + 1, 1);
        BAR();
        __builtin_amdgcn_s_setprio(1);
        #pragma unroll
        for (int m = 0; m < 4; ++m)
            #pragma unroll
            for (int n = 0; n < 4; ++n)
                acc[m][n] = __builtin_amdgcn_mfma_f32_16x16x32_bf16(
                    af[m], bf[n], acc[m][n], 0, 0, 0);
        __builtin_amdgcn_s_setprio(0);
        BAR();
        // ---- ph2: m4-7 x kk0 (B held in regs; stages (t+1).Bk1)
        rdA(b, 0, 1);
        if (t + 1 < NT) stB(t + 1, 1);
        BAR();
        __builtin_amdgcn_s_setprio(1);
        #pragma unroll
        for (int m = 0; m < 4; ++m)
            #pragma unroll
            for (int n = 0; n < 4; ++n)
                acc[4 + m][n] = __builtin_amdgcn_mfma_f32_16x16x32_bf16(
                    af[m], bf[n], acc[4 + m][n], 0, 0, 0);
        __builtin_amdgcn_s_setprio(0);
        if (t < NT - 1) asm volatile("s_waitcnt vmcnt(8)" ::: "memory");
        else            asm volatile("s_waitcnt vmcnt(0)" ::: "memory");
        __builtin_amdgcn_sched_barrier(0);
        BAR();   // t.Ak1/Bk1 landed for all waves -> ph3 may read
        // ---- ph3: m0-3 x kk1 (stages (t+2).Ak0 over dead t.Ak0)
        rdA(b, 1, 0); rdB(b, 1);
        if (t + 2 < NT) stA(t + 2, 0);
        BAR();
        __builtin_amdgcn_s_setprio(1);
        #pragma unroll
        for (int m = 0; m < 4; ++m)
            #pragma unroll
            for (int n = 0; n < 4; ++n)
                acc[m][n] = __builtin_amdgcn_mfma_f32_16x16x32_bf16(
                    af[m], bf[n], acc[m][n], 0, 0, 0);
        __builtin_amdgcn_s_setprio(0);
        BAR();
        // ---- ph4: m4-7 x kk1 (stages (t+2).Bk0 over dead t.Bk0)
        rdA(b, 1, 1);
        if (t + 2 < NT) stB(t + 2, 0);
        BAR();
        __builtin_amdgcn_s_setprio(1);
        #pragma unroll
        for (int m = 0; m < 4; ++m)
            #pragma unroll
            for (int n = 0; n < 4; ++n)
                acc[4 + m][n] = __builtin_amdgcn_mfma_f32_16x16x32_bf16(
                    af[m], bf[n], acc[4 + m][n], 0, 0, 0);
        __builtin_amdgcn_s_setprio(0);
        if (t < NT - 2) asm volatile("s_waitcnt vmcnt(8)" ::: "memory");
        else            asm volatile("s_waitcnt vmcnt(0)" ::: "memory");
        __builtin_amdgcn_sched_barrier(0);
        BAR();   // (t+1).Ak0/Bk0 landed -> next tile ph1 may read
    }

    // epilogue: C/D layout col=lane&15, row=q*4+reg (verified m89)
    const float* bias = (z == 0) ? b0 : (z == 1) ? b1 : b2;
    TOUT* Cb = (((z == 0) ? c0 : (z == 1) ? c1 : c2) + (long)z * bsC)
               + m0 * ldc + n0;
    #pragma unroll
    for (int m = 0; m < 8; ++m) {
        #pragma unroll
        for (int r = 0; r < 4; ++r) {
            int row = wm * 128 + m * 16 + q * 4 + r;
            float rsum = 0.f;
            #pragma unroll
            for (int n = 0; n < 4; ++n) {
                int col = wn * 64 + n * 16 + lrow;
                float v = acc[m][n][r] * scale;
                if constexpr (BIAS == 1) v += bias[n0 + col];
                if constexpr (EPI == 1) { v = __expf(v); rsum += v; }
                if constexpr (sizeof(TOUT) == 2)
                    Cb[(long)row * ldc + col] = to_bf16(v);
                else
                    Cb[(long)row * ldc + col] = v;
            }
            if constexpr (EPI == 1) {
                rsum += __shfl_xor(rsum, 1);
                rsum += __shfl_xor(rsum, 2);
                rsum += __shfl_xor(rsum, 4);
                rsum += __shfl_xor(rsum, 8);
                if (lrow == 0) {
                    int j = (int)(n0 >> 6) + wn;     // 0..31
                    ps[((long)z * 32 + j) * 2048 + m0 + row] = rsum;
                }
            }
        }
    }
}

// ===================== gemm97 (proven 2-barrier core) ======================
// BIAS: 0=none, 2=row bias b0[m]. EPI: 0=plain, 2=v *= 1/rs[row].
template<int BIAS, int EPI, typename TOUT>
__global__ __launch_bounds__(256, 3)
void gemm97(const short* __restrict__ A, long lda, long bsA,
            const short* __restrict__ B, long ldb, long bsB,
            const float* __restrict__ b0,
            TOUT* __restrict__ C, long ldc, long bsC, int K, float scale,
            const float* __restrict__ rs, long rsLD)
{
    __shared__ __align__(16) short As[128 * 64];
    __shared__ __align__(16) short Bs[128 * 64];

    const int tid = threadIdx.x;
    const int z = blockIdx.z;

    const int gx = gridDim.x;
    const int nwg = gx * gridDim.y;
    const int id = blockIdx.y * gx + blockIdx.x;
    const int id2 = (id & 7) * (nwg >> 3) + (id >> 3);
    const long m0 = (long)(id2 / gx) * 128;
    const long n0 = (long)(id2 % gx) * 128;

    const short* Ab = A + (long)z * bsA + m0 * lda;
    const short* Bb = B + (long)z * bsB + n0 * ldb;

    const int wv = tid >> 6;
    const int lane = tid & 63;
    const int wr = (wv >> 1) * 64;
    const int wc = (wv & 1) * 64;
    const int lrow = lane & 15;
    const int q = lane >> 4;

    const int NT = K >> 6;

    auto stage = [&](int t) {
        const long k0 = (long)t * 64;
        #pragma unroll
        for (int i = 0; i < 4; ++i) {
            int s = i * 256 + tid;
            int row = s >> 3;
            int src = (s & 7) ^ (row & 7);
            gload_lds16(Ab + (long)row * lda + k0 + src * 8, &As[s * 8]);
        }
        #pragma unroll
        for (int i = 0; i < 4; ++i) {
            int s = i * 256 + tid;
            int row = s >> 3;
            int src = (s & 7) ^ (row & 7);
            gload_lds16(Bb + (long)row * ldb + k0 + src * 8, &Bs[s * 8]);
        }
    };

    f32x4 acc[4][4] = {};

    for (int t = 0; t < NT; ++t) {
        if (t) {
            // all waves' reads of the buffer consumed (their MFMAs issued
            // => compiler lgkm waits done) before anyone restages.
            BAR();
        }
        stage(t);
        asm volatile("s_waitcnt vmcnt(0)" ::: "memory");
        __builtin_amdgcn_sched_barrier(0);
        BAR();

        bf16x8 af[4][2], bf[4][2];
        #pragma unroll
        for (int m = 0; m < 4; ++m) {
            int row = wr + m * 16 + lrow;
            #pragma unroll
            for (int kk = 0; kk < 2; ++kk) {
                int ch = (kk * 4 + q) ^ (row & 7);
                af[m][kk] = *(const bf16x8*)&As[row * 64 + ch * 8];
            }
        }
        #pragma unroll
        for (int n = 0; n < 4; ++n) {
            int row = wc + n * 16 + lrow;
            #pragma unroll
            for (int kk = 0; kk < 2; ++kk) {
                int ch = (kk * 4 + q) ^ (row & 7);
                bf[n][kk] = *(const bf16x8*)&Bs[row * 64 + ch * 8];
            }
        }

        __builtin_amdgcn_s_setprio(1);
        #pragma unroll
        for (int m = 0; m < 4; ++m)
            #pragma unroll
            for (int n = 0; n < 4; ++n)
                #pragma unroll
                for (int kk = 0; kk < 2; ++kk)
                    acc[m][n] = __builtin_amdgcn_mfma_f32_16x16x32_bf16(
                        af[m][kk], bf[n][kk], acc[m][n], 0, 0, 0);
        __builtin_amdgcn_s_setprio(0);
    }

    TOUT* Cb = C + (long)z * bsC + m0 * ldc + n0;
    #pragma unroll
    for (int m = 0; m < 4; ++m) {
        #pragma unroll
        for (int r = 0; r < 4; ++r) {
            int row = wr + m * 16 + q * 4 + r;
            float iv = 1.0f;
            if constexpr (EPI == 2)
                iv = 1.0f / rs[(long)z * rsLD + m0 + row];
            #pragma unroll
            for (int n = 0; n < 4; ++n) {
                int col = wc + n * 16 + lrow;
                float v = acc[m][n][r] * scale;
                if constexpr (BIAS == 2) v += b0[m0 + row];
                if constexpr (EPI == 2) v *= iv;
                if constexpr (sizeof(TOUT) == 2)
                    Cb[(long)row * ldc + col] = to_bf16(v);
                else
                    Cb[(long)row * ldc + col] = v;
            }
        }
    }
}

// merged cvt: grid (512, 11). y<8: x chunks (fp32->bf16). y=8,9,10: Wq,Wk,Wv.
__global__ __launch_bounds__(256)
void cvt_all(const float* __restrict__ x,
             const float* __restrict__ wq, const float* __restrict__ wk,
             const float* __restrict__ wv, short* __restrict__ dst)
{
    const int y = blockIdx.y;
    const float* src;
    long dstOff8;
    long i;
    if (y < 8) {
        src = x;
        i = ((long)y * 512 + blockIdx.x) * 256 + threadIdx.x;
        dstOff8 = 0;
    } else {
        src = (y == 8) ? wq : (y == 9) ? wk : wv;
        i = (long)blockIdx.x * 256 + threadIdx.x;
        dstOff8 = (8l * 1024 * 1024 + (long)(y - 8) * 1024 * 1024) / 8;
    }
    float4 a = ((const float4*)src)[2 * i];
    float4 b = ((const float4*)src)[2 * i + 1];
    bf16x8 o = { to_bf16(a.x), to_bf16(a.y), to_bf16(a.z), to_bf16(a.w),
                 to_bf16(b.x), to_bf16(b.y), to_bf16(b.z), to_bf16(b.w) };
    *(bf16x8*)&dst[(dstOff8 + i) * 8] = o;
}

// rs[row] = sum_{j<32} ps[(z*32+j)*2048 + r]
__global__ __launch_bounds__(256)
void reduce_rs(const float* __restrict__ ps, float* __restrict__ rs)
{
    int row = blockIdx.x * 256 + threadIdx.x;   // 0..8191
    int z = row >> 11, r = row & 2047;
    const float* p = ps + (long)z * 32 * 2048 + r;
    float s = 0.f;
    #pragma unroll
    for (int j = 0; j < 32; ++j) s += p[j * 2048];
    rs[row] = s;
}

extern "C" void kernel_launch(void* const* d_in, const int* in_sizes, int n_in,
                              void* d_out, int out_size, void* d_ws, size_t ws_size,
                              hipStream_t stream)
{
    (void)in_sizes; (void)n_in; (void)out_size; (void)ws_size;

    const float* x  = (const float*)d_in[0];
    const float* Wq = (const float*)d_in[1];
    const float* bq = (const float*)d_in[2];
    const float* Wk = (const float*)d_in[3];
    const float* bk = (const float*)d_in[4];
    const float* Wv = (const float*)d_in[5];
    const float* bv = (const float*)d_in[6];
    float* out = (float*)d_out;

    const int S = 2048, E = 1024;
    const long M1 = 1024l * 1024;

    // ws regions (shorts)
    short* w  = (short*)d_ws;
    short* Q  = w;                  // [4][2048][1024]  (16MB)
    short* Kb = w + 8 * M1;         // [4][2048][1024]  (16MB)
    short* P  = w + 16 * M1;        // [4][2048][2048]  (32MB) exp(scores)
    float* rs = (float*)w;          // [4][2048] fp32 over dead Q
    short* VT = w + 8 * M1;         // [4][1024][2048] over dead K (post-scores)

    // d_out scratch (xb/Wb last read by VT-GEMM; psum by reduce_rs)
    short* dows = (short*)d_out;
    short* xb = dows;               // [8192][1024] bf16 (16MB)
    short* Wb = dows + 8 * M1;      // Wq,Wk,Wv bf16 (3 x 2MB)
    float* psum = (float*)(dows + 11 * M1);   // [4][32][2048] fp32 (1MB)

    dim3 blk(256), blk5(512);

    // 1. convert inputs to bf16
    cvt_all<<<dim3(512, 11), blk, 0, stream>>>(x, Wq, Wk, Wv, xb);

    // 2. Q,K projections (M=8192,N=1024,K=1024): 8-phase, grid 4x32x2 = 256
    gemm256<1, 0, short><<<dim3(4, 32, 2), blk5, 0, stream>>>(
        xb, E, 0, Wb, E, M1, bq, bk, nullptr, Q, Kb, nullptr, E, 0, E, 1.0f,
        nullptr);

    // 3. scores: P[z] = exp(Q K^T / 32) + psum (M=N=2048,K=1024): 8x8x4 = 256
    gemm256<0, 1, short><<<dim3(8, 8, 4), blk5, 0, stream>>>(
        Q, E, 2 * M1, Kb, E, 2 * M1, nullptr, nullptr, nullptr,
        P, P, P, S, 4 * M1, E, 0.03125f, psum);

    // 4. VT[z] = Wv xb[z]^T + bv (row bias) (M=1024,N=2048,K=1024): 16x8x4
    gemm97<2, 0, short><<<dim3(16, 8, 4), blk, 0, stream>>>(
        Wb + 2 * M1, E, 0, xb, E, 2 * M1, bv, VT, S, 2 * M1, E, 1.0f,
        nullptr, 0);

    // 5. rs[row] = sum of 32 partials (over dead Q)
    reduce_rs<<<dim3(32), blk, 0, stream>>>(psum, rs);

    // 6. out[z] = (P[z] VT[z]^T) / rs (M=2048,N=1024,K=2048): 8x16x4, fp32
    gemm97<0, 2, float><<<dim3(8, 16, 4), blk, 0, stream>>>(
        P, S, 4 * M1, VT, S, 2 * M1, nullptr, out, E, 2 * M1, S, 1.0f,
        rs, S);
}